// Round 8
// baseline (457.413 us; speedup 1.0000x reference)
//
#include <hip/hip_runtime.h>

#define NN 20000      // nodes
#define NE 640000     // edges (without self loops)
#define NEE 660000    // edges + self loops
#define NP 200000     // drug pairs
#define NEG 0.2f      // leaky relu slope

// ---------------- CSR build ----------------
__global__ void k_hist(const int* __restrict__ ei, int* __restrict__ cnt) {
  int i = blockIdx.x * 256 + threadIdx.x;
  if (i >= NEE) return;
  int d = (i < NE) ? ei[NE + i] : (i - NE);
  atomicAdd(&cnt[d], 1);
}

__global__ __launch_bounds__(1024) void k_scan(const int* __restrict__ cnt, int* __restrict__ rp) {
  __shared__ int ps[1024];
  const int CH = 20;  // 1024*20 = 20480 >= 20000
  int t = threadIdx.x;
  int lo = t * CH, hi = lo + CH;
  if (hi > NN) hi = NN;
  if (lo > NN) lo = NN;
  int s = 0;
  for (int i = lo; i < hi; ++i) s += cnt[i];
  ps[t] = s;
  __syncthreads();
  for (int off = 1; off < 1024; off <<= 1) {
    int v = (t >= off) ? ps[t - off] : 0;
    __syncthreads();
    ps[t] += v;
    __syncthreads();
  }
  int run = (t > 0) ? ps[t - 1] : 0;
  for (int i = lo; i < hi; ++i) { rp[i] = run; run += cnt[i]; }
  if (t == 1023) rp[NN] = ps[1023];
}

__global__ void k_scatter(const int* __restrict__ ei, const int* __restrict__ rp,
                          int* __restrict__ cur, int* __restrict__ col,
                          int* __restrict__ dstv) {
  int i = blockIdx.x * 256 + threadIdx.x;
  if (i >= NEE) return;
  int s, d;
  if (i < NE) { s = ei[i]; d = ei[NE + i]; } else { s = i - NE; d = s; }
  int pos = atomicAdd(&cur[d], 1);
  col[rp[d] + pos] = s;
  dstv[rp[d] + pos] = d;
}

// ---------------- weight prep: pad Wp2 [64][86] -> [64][88], bp2 -> [88] ----------------
__global__ void k_prep(const float* __restrict__ Wp2, const float* __restrict__ bp2,
                       float* __restrict__ Wp2p, float* __restrict__ bp2p) {
  int i = blockIdx.x * 256 + threadIdx.x;
  if (i < 64 * 88) { int t = i / 88, o = i % 88; Wp2p[i] = (o < 86) ? Wp2[t * 86 + o] : 0.f; }
  if (i < 88) bp2p[i] = (i < 86) ? bp2[i] : 0.f;
}

// ---------------- GEMM1: h1 = x @ W1  [20000,256]x[256,256], + alphas ----------------
// h1 is stored HEAD-MAJOR: h1h[head][n][64] so each head's slice is a contiguous 5 MB.
__global__ __launch_bounds__(256) void k_gemm1(
    const float* __restrict__ x, const float* __restrict__ W1,
    const float* __restrict__ as1, const float* __restrict__ ad1,
    float* __restrict__ h1h, float* __restrict__ AS1, float* __restrict__ AD1) {
  __shared__ float xsT[256][20];  // [k][row], pad 20 keeps 16B row alignment
  int c = threadIdx.x;            // output col 0..255
  int base = blockIdx.x * 16;     // 16 rows per block
  for (int i = threadIdx.x; i < 16 * 256; i += 256) {
    int r = i >> 8, k = i & 255;
    xsT[k][r] = x[(base + r) * 256 + k];
  }
  __syncthreads();
  float acc[16];
#pragma unroll
  for (int r = 0; r < 16; ++r) acc[r] = 0.f;
#pragma unroll 2
  for (int k = 0; k < 256; ++k) {
    float wv = W1[k * 256 + c];
    const float4* xr = (const float4*)&xsT[k][0];
    float4 x0 = xr[0], x1 = xr[1], x2 = xr[2], x3 = xr[3];
    acc[0] += x0.x * wv; acc[1] += x0.y * wv; acc[2] += x0.z * wv; acc[3] += x0.w * wv;
    acc[4] += x1.x * wv; acc[5] += x1.y * wv; acc[6] += x1.z * wv; acc[7] += x1.w * wv;
    acc[8] += x2.x * wv; acc[9] += x2.y * wv; acc[10] += x2.z * wv; acc[11] += x2.w * wv;
    acc[12] += x3.x * wv; acc[13] += x3.y * wv; acc[14] += x3.z * wv; acc[15] += x3.w * wv;
  }
  int head = c >> 6, cc = c & 63;
  float asv = as1[c];  // flat [head][c&63] == c
  float adv = ad1[c];
#pragma unroll
  for (int r = 0; r < 16; ++r) {
    h1h[((size_t)head * NN + (base + r)) * 64 + cc] = acc[r];
    float vs = acc[r] * asv, vd = acc[r] * adv;
#pragma unroll
    for (int off = 32; off > 0; off >>= 1) {
      vs += __shfl_xor(vs, off);
      vd += __shfl_xor(vd, off);
    }
    if ((c & 63) == 0) {
      AS1[(base + r) * 4 + head] = vs;
      AD1[(base + r) * 4 + head] = vd;
    }
  }
}

// ---------------- edge weights layer 1: p = exp(lrelu(AS1[s]+AD1[d])), 4 heads ------------
__global__ void k_edgew1(const int* __restrict__ col, const int* __restrict__ dstv,
                         const float* __restrict__ AS1, const float* __restrict__ AD1,
                         float* __restrict__ w1) {
  int i = blockIdx.x * 256 + threadIdx.x;
  if (i >= NEE) return;
  int s = col[i], d = dstv[i];
  float4 as = *(const float4*)(AS1 + s * 4);
  float4 ad = *(const float4*)(AD1 + d * 4);
  float e0 = as.x + ad.x, e1 = as.y + ad.y, e2 = as.z + ad.z, e3 = as.w + ad.w;
  e0 = e0 > 0.f ? e0 : NEG * e0;
  e1 = e1 > 0.f ? e1 : NEG * e1;
  e2 = e2 > 0.f ? e2 : NEG * e2;
  e3 = e3 > 0.f ? e3 : NEG * e3;
  w1[0 * NEE + i] = __expf(e0);
  w1[1 * NEE + i] = __expf(e1);
  w1[2 * NEE + i] = __expf(e2);
  w1[3 * NEE + i] = __expf(e3);
}

// ---------------- GAT layer-1 aggregation: 4 edges x 16 lanes per wave ----------------
__global__ __launch_bounds__(256) void k_agg1(
    const int* __restrict__ rp, const int* __restrict__ col,
    const float* __restrict__ w1, const float* __restrict__ h1h,
    const float* __restrict__ b1, float* __restrict__ out) {
  int wave = threadIdx.x >> 6, lane = threadIdx.x & 63;
  int head = blockIdx.y;
  int n = blockIdx.x * 4 + wave;
  int g = lane >> 4, c4 = (lane & 15) * 4;
  int e0 = rp[n], e1 = rp[n + 1];
  const float* hs = h1h + (size_t)head * NN * 64;
  const float* wp = w1 + (size_t)head * NEE;
  float ax = 0.f, ay = 0.f, az = 0.f, aw = 0.f, den = 0.f;
#pragma unroll 2
  for (int e = e0; e < e1; e += 4) {
    int ee = e + g;
    bool valid = ee < e1;
    int ec = valid ? ee : e1 - 1;
    int s = col[ec];
    float p = valid ? wp[ec] : 0.f;
    float4 hv = *(const float4*)(hs + (size_t)s * 64 + c4);
    ax += p * hv.x; ay += p * hv.y; az += p * hv.z; aw += p * hv.w;
    den += p;
  }
  ax += __shfl_xor(ax, 16); ax += __shfl_xor(ax, 32);
  ay += __shfl_xor(ay, 16); ay += __shfl_xor(ay, 32);
  az += __shfl_xor(az, 16); az += __shfl_xor(az, 32);
  aw += __shfl_xor(aw, 16); aw += __shfl_xor(aw, 32);
  den += __shfl_xor(den, 16); den += __shfl_xor(den, 32);
  if (lane < 16) {
    float inv = 1.f / den;
    int cbase = head * 64 + c4;
    float4 bv = *(const float4*)(b1 + cbase);
    float4 o;
    o.x = ax * inv + bv.x; o.y = ay * inv + bv.y;
    o.z = az * inv + bv.z; o.w = aw * inv + bv.w;
    o.x = o.x > 0.f ? o.x : __expf(o.x) - 1.f;
    o.y = o.y > 0.f ? o.y : __expf(o.y) - 1.f;
    o.z = o.z > 0.f ? o.z : __expf(o.z) - 1.f;
    o.w = o.w > 0.f ? o.w : __expf(o.w) - 1.f;
    *(float4*)(out + (size_t)n * 256 + cbase) = o;
  }
}

// ---------------- GEMM2: h2 = h1act @ W2  [20000,256]x[256,64], + alphas ----------------
__global__ __launch_bounds__(256) void k_gemm2(
    const float* __restrict__ h1a, const float* __restrict__ W2,
    const float* __restrict__ as2, const float* __restrict__ ad2,
    float* __restrict__ h2, float* __restrict__ AS2, float* __restrict__ AD2) {
  __shared__ float xsT[256][20];
  int tid = threadIdx.x;
  int c = tid & 63, w = tid >> 6;  // wave w handles rows 4w..4w+3
  int base = blockIdx.x * 16;
  for (int i = tid; i < 16 * 256; i += 256) {
    int r = i >> 8, k = i & 255;
    xsT[k][r] = h1a[(base + r) * 256 + k];
  }
  __syncthreads();
  float acc[4] = {0.f, 0.f, 0.f, 0.f};
#pragma unroll 2
  for (int k = 0; k < 256; ++k) {
    float wv = W2[k * 64 + c];
    float4 xv = *(const float4*)&xsT[k][w * 4];
    acc[0] += xv.x * wv; acc[1] += xv.y * wv; acc[2] += xv.z * wv; acc[3] += xv.w * wv;
  }
  float asv = as2[c], adv = ad2[c];
#pragma unroll
  for (int rr = 0; rr < 4; ++rr) {
    int row = base + w * 4 + rr;
    h2[row * 64 + c] = acc[rr];
    float vs = acc[rr] * asv, vd = acc[rr] * adv;
#pragma unroll
    for (int off = 32; off > 0; off >>= 1) {
      vs += __shfl_xor(vs, off);
      vd += __shfl_xor(vd, off);
    }
    if (c == 0) { AS2[row] = vs; AD2[row] = vd; }
  }
}

// ---------------- edge weights layer 2 ----------------
__global__ void k_edgew2(const int* __restrict__ col, const int* __restrict__ dstv,
                         const float* __restrict__ AS2, const float* __restrict__ AD2,
                         float* __restrict__ w2) {
  int i = blockIdx.x * 256 + threadIdx.x;
  if (i >= NEE) return;
  int s = col[i], d = dstv[i];
  float ev = AS2[s] + AD2[d];
  ev = ev > 0.f ? ev : NEG * ev;
  w2[i] = __expf(ev);
}

// ---------------- GAT layer-2 aggregation: 4 edges x 16 lanes per wave ----------------
__global__ __launch_bounds__(256) void k_agg2(
    const int* __restrict__ rp, const int* __restrict__ col,
    const float* __restrict__ w2, const float* __restrict__ h2,
    const float* __restrict__ b2, float* __restrict__ out) {
  int wave = threadIdx.x >> 6, lane = threadIdx.x & 63;
  int n = blockIdx.x * 4 + wave;
  int g = lane >> 4, c4 = (lane & 15) * 4;
  int e0 = rp[n], e1 = rp[n + 1];
  float ax = 0.f, ay = 0.f, az = 0.f, aw = 0.f, den = 0.f;
#pragma unroll 2
  for (int e = e0; e < e1; e += 4) {
    int ee = e + g;
    bool valid = ee < e1;
    int ec = valid ? ee : e1 - 1;
    int s = col[ec];
    float p = valid ? w2[ec] : 0.f;
    float4 hv = *(const float4*)(h2 + (size_t)s * 64 + c4);
    ax += p * hv.x; ay += p * hv.y; az += p * hv.z; aw += p * hv.w;
    den += p;
  }
  ax += __shfl_xor(ax, 16); ax += __shfl_xor(ax, 32);
  ay += __shfl_xor(ay, 16); ay += __shfl_xor(ay, 32);
  az += __shfl_xor(az, 16); az += __shfl_xor(az, 32);
  aw += __shfl_xor(aw, 16); aw += __shfl_xor(aw, 32);
  den += __shfl_xor(den, 16); den += __shfl_xor(den, 32);
  if (lane < 16) {
    float inv = 1.f / den;
    float4 bv = *(const float4*)(b2 + c4);
    float4 o;
    o.x = ax * inv + bv.x; o.y = ay * inv + bv.y;
    o.z = az * inv + bv.z; o.w = aw * inv + bv.w;
    o.x = o.x > 0.f ? o.x : __expf(o.x) - 1.f;
    o.y = o.y > 0.f ? o.y : __expf(o.y) - 1.f;
    o.z = o.z > 0.f ? o.z : __expf(o.z) - 1.f;
    o.w = o.w > 0.f ? o.w : __expf(o.w) - 1.f;
    *(float4*)(out + (size_t)n * 64 + c4) = o;
  }
}

// ---------------- pair MLP v7: pair split across 4 waves ----------------
// Block = 256 threads = 4 waves, 64 pairs (200000 = 64*3125 exactly -> no bounds check).
// Wave hu computes z quarter [16 units] then output-column chunk [22 of 88 padded cols].
// Live set: acc[16]+ck[16] = 32 floats -> allocator can batch all 4 float4 gathers
// (round-7 failure: acc[32]+ck[16] = 48 > the 44 VGPRs the allocator chose).
// 16.9 KB LDS, 8 blocks/CU -> 32 waves/CU resident.
#define PB 256

__global__ __launch_bounds__(PB) void k_pairs(
    const int* __restrict__ pairs, const float* __restrict__ h2a,
    const float* __restrict__ Wp1, const float* __restrict__ bp1,
    const float* __restrict__ Wp2p, const float* __restrict__ bp2p,
    float* __restrict__ out) {
  __shared__ float zt[64][66];  // [t][pair]
  int tid = threadIdx.x;
  int pp = tid & 63;                                      // pair within block
  int hu = __builtin_amdgcn_readfirstlane(tid >> 6);      // wave id 0..3, provably uniform
  int p = blockIdx.x * 64 + pp;
  int pi = pairs[2 * p], pj = pairs[2 * p + 1];
  const float* rowi = h2a + pi * 64;
  const float* rowj = h2a + pj * 64;

  // layer 1: z[hu*16+u] = relu(bp1 + sum_k comb[k]*Wp1[k][hu*16+u])
  {
    float acc[16];
#pragma unroll
    for (int u = 0; u < 16; ++u) acc[u] = bp1[hu * 16 + u];
#pragma unroll 1
    for (int g = 0; g < 8; ++g) {  // 8 chunks of 16 k over comb(128)=[rowi,rowj]
      const float* src = (g < 4) ? rowi : rowj;
      int off = (g & 3) * 16;
      float ck[16];
#pragma unroll
      for (int q = 0; q < 4; ++q) {
        float4 v = *(const float4*)(src + off + q * 4);
        ck[q * 4] = v.x; ck[q * 4 + 1] = v.y; ck[q * 4 + 2] = v.z; ck[q * 4 + 3] = v.w;
      }
      int k0 = g * 16;
#pragma unroll
      for (int kk = 0; kk < 16; ++kk)
#pragma unroll
        for (int u = 0; u < 16; ++u)
          acc[u] += ck[kk] * Wp1[(k0 + kk) * 64 + hu * 16 + u];  // uniform, u-consecutive
    }
#pragma unroll
    for (int u = 0; u < 16; ++u) zt[hu * 16 + u][pp] = fmaxf(acc[u], 0.f);
  }
  __syncthreads();

  // layer 2: out[p][hu*22 + j] = bp2 + sum_t z[t]*Wp2p[t][hu*22+j] (padded to 88 cols)
  {
    float acc2[22];
#pragma unroll
    for (int j = 0; j < 22; ++j) acc2[j] = bp2p[hu * 22 + j];
#pragma unroll 2
    for (int t = 0; t < 64; ++t) {
      float zv = zt[t][pp];
#pragma unroll
      for (int j = 0; j < 22; ++j)
        acc2[j] += zv * Wp2p[t * 88 + hu * 22 + j];  // uniform, j-consecutive
    }
    int o0 = hu * 22;
#pragma unroll
    for (int j = 0; j < 22; ++j) {
      int o = o0 + j;
      if (o < 86) out[(size_t)p * 86 + o] = acc2[j];
    }
  }
}

extern "C" void kernel_launch(void* const* d_in, const int* in_sizes, int n_in,
                              void* d_out, int out_size, void* d_ws, size_t ws_size,
                              hipStream_t stream) {
  (void)in_sizes; (void)n_in; (void)out_size; (void)ws_size;
  const float* x      = (const float*)d_in[0];
  const int*   ei     = (const int*)d_in[1];
  const int*   pairs  = (const int*)d_in[2];
  const float* W1     = (const float*)d_in[3];
  const float* a_src1 = (const float*)d_in[4];
  const float* a_dst1 = (const float*)d_in[5];
  const float* b1     = (const float*)d_in[6];
  const float* W2     = (const float*)d_in[7];
  const float* a_src2 = (const float*)d_in[8];
  const float* a_dst2 = (const float*)d_in[9];
  const float* b2     = (const float*)d_in[10];
  const float* Wp1    = (const float*)d_in[11];
  const float* bp1    = (const float*)d_in[12];
  const float* Wp2    = (const float*)d_in[13];
  const float* bp2    = (const float*)d_in[14];
  float* out = (float*)d_out;

  char* w = (char*)d_ws;
  auto alloc = [&](size_t bytes) -> void* {
    void* pp = (void*)w;
    w += (bytes + 255) & ~(size_t)255;
    return pp;
  };
  float* h1    = (float*)alloc((size_t)NN * 256 * 4);  // head-major [4][NN][64]
  float* AS1   = (float*)alloc((size_t)NN * 4 * 4);
  float* AD1   = (float*)alloc((size_t)NN * 4 * 4);
  float* h1agg = (float*)alloc((size_t)NN * 256 * 4);
  float* h2    = (float*)alloc((size_t)NN * 64 * 4);
  float* AS2   = (float*)alloc((size_t)NN * 4);
  float* AD2   = (float*)alloc((size_t)NN * 4);
  float* h2agg = (float*)alloc((size_t)NN * 64 * 4);
  int*   rp    = (int*)alloc((size_t)(NN + 1) * 4);
  int*   cnt   = (int*)alloc((size_t)NN * 4);
  int*   cur   = (int*)alloc((size_t)NN * 4);
  int*   col   = (int*)alloc((size_t)NEE * 4);
  int*   dstv  = (int*)alloc((size_t)NEE * 4);
  float* w1    = (float*)alloc((size_t)4 * NEE * 4);
  float* w2    = (float*)alloc((size_t)NEE * 4);
  float* Wp2p  = (float*)alloc(64 * 88 * 4);
  float* bp2p  = (float*)alloc(88 * 4);

  hipMemsetAsync(cnt, 0, (size_t)NN * 4, stream);
  hipMemsetAsync(cur, 0, (size_t)NN * 4, stream);

  const int EB = (NEE + 255) / 256;  // 2579
  k_hist<<<EB, 256, 0, stream>>>(ei, cnt);
  k_scan<<<1, 1024, 0, stream>>>(cnt, rp);
  k_scatter<<<EB, 256, 0, stream>>>(ei, rp, cur, col, dstv);
  k_prep<<<23, 256, 0, stream>>>(Wp2, bp2, Wp2p, bp2p);

  k_gemm1<<<NN / 16, 256, 0, stream>>>(x, W1, a_src1, a_dst1, h1, AS1, AD1);
  k_edgew1<<<EB, 256, 0, stream>>>(col, dstv, AS1, AD1, w1);
  k_agg1<<<dim3(NN / 4, 4), 256, 0, stream>>>(rp, col, w1, h1, b1, h1agg);

  k_gemm2<<<NN / 16, 256, 0, stream>>>(h1agg, W2, a_src2, a_dst2, h2, AS2, AD2);
  k_edgew2<<<EB, 256, 0, stream>>>(col, dstv, AS2, AD2, w2);
  k_agg2<<<NN / 4, 256, 0, stream>>>(rp, col, w2, h2, b2, h2agg);

  k_pairs<<<NP / 64, PB, 0, stream>>>(pairs, h2agg, Wp1, bp1, Wp2p, bp2p, out);
}

// Round 9
// 427.406 us; speedup vs baseline: 1.0702x; 1.0702x over previous
//
#include <hip/hip_runtime.h>

#define NN 20000      // nodes
#define NE 640000     // edges (without self loops)
#define NEE 660000    // edges + self loops
#define NP 200000     // drug pairs
#define NEG 0.2f      // leaky relu slope

// ---------------- CSR build ----------------
__global__ void k_hist(const int* __restrict__ ei, int* __restrict__ cnt) {
  int i = blockIdx.x * 256 + threadIdx.x;
  if (i >= NEE) return;
  int d = (i < NE) ? ei[NE + i] : (i - NE);
  atomicAdd(&cnt[d], 1);
}

__global__ __launch_bounds__(1024) void k_scan(const int* __restrict__ cnt, int* __restrict__ rp) {
  __shared__ int ps[1024];
  const int CH = 20;  // 1024*20 = 20480 >= 20000
  int t = threadIdx.x;
  int lo = t * CH, hi = lo + CH;
  if (hi > NN) hi = NN;
  if (lo > NN) lo = NN;
  int s = 0;
  for (int i = lo; i < hi; ++i) s += cnt[i];
  ps[t] = s;
  __syncthreads();
  for (int off = 1; off < 1024; off <<= 1) {
    int v = (t >= off) ? ps[t - off] : 0;
    __syncthreads();
    ps[t] += v;
    __syncthreads();
  }
  int run = (t > 0) ? ps[t - 1] : 0;
  for (int i = lo; i < hi; ++i) { rp[i] = run; run += cnt[i]; }
  if (t == 1023) rp[NN] = ps[1023];
}

__global__ void k_scatter(const int* __restrict__ ei, const int* __restrict__ rp,
                          int* __restrict__ cur, int* __restrict__ col,
                          int* __restrict__ dstv) {
  int i = blockIdx.x * 256 + threadIdx.x;
  if (i >= NEE) return;
  int s, d;
  if (i < NE) { s = ei[i]; d = ei[NE + i]; } else { s = i - NE; d = s; }
  int pos = atomicAdd(&cur[d], 1);
  col[rp[d] + pos] = s;
  dstv[rp[d] + pos] = d;
}

// ---------------- weight prep: pad Wp2 [64][86] -> [64][96], bp2 -> [96] ----------------
__global__ void k_prep(const float* __restrict__ Wp2, const float* __restrict__ bp2,
                       float* __restrict__ Wp2p, float* __restrict__ bp2p) {
  int i = blockIdx.x * 256 + threadIdx.x;
  if (i < 64 * 96) { int t = i / 96, o = i % 96; Wp2p[i] = (o < 86) ? Wp2[t * 86 + o] : 0.f; }
  if (i < 96) bp2p[i] = (i < 86) ? bp2[i] : 0.f;
}

// ---------------- GEMM1: h1 = x @ W1  [20000,256]x[256,256], + alphas ----------------
// h1 is stored HEAD-MAJOR: h1h[head][n][64] so each head's slice is a contiguous 5 MB.
__global__ __launch_bounds__(256) void k_gemm1(
    const float* __restrict__ x, const float* __restrict__ W1,
    const float* __restrict__ as1, const float* __restrict__ ad1,
    float* __restrict__ h1h, float* __restrict__ AS1, float* __restrict__ AD1) {
  __shared__ float xsT[256][20];  // [k][row], pad 20 keeps 16B row alignment
  int c = threadIdx.x;            // output col 0..255
  int base = blockIdx.x * 16;     // 16 rows per block
  for (int i = threadIdx.x; i < 16 * 256; i += 256) {
    int r = i >> 8, k = i & 255;
    xsT[k][r] = x[(base + r) * 256 + k];
  }
  __syncthreads();
  float acc[16];
#pragma unroll
  for (int r = 0; r < 16; ++r) acc[r] = 0.f;
#pragma unroll 2
  for (int k = 0; k < 256; ++k) {
    float wv = W1[k * 256 + c];
    const float4* xr = (const float4*)&xsT[k][0];
    float4 x0 = xr[0], x1 = xr[1], x2 = xr[2], x3 = xr[3];
    acc[0] += x0.x * wv; acc[1] += x0.y * wv; acc[2] += x0.z * wv; acc[3] += x0.w * wv;
    acc[4] += x1.x * wv; acc[5] += x1.y * wv; acc[6] += x1.z * wv; acc[7] += x1.w * wv;
    acc[8] += x2.x * wv; acc[9] += x2.y * wv; acc[10] += x2.z * wv; acc[11] += x2.w * wv;
    acc[12] += x3.x * wv; acc[13] += x3.y * wv; acc[14] += x3.z * wv; acc[15] += x3.w * wv;
  }
  int head = c >> 6, cc = c & 63;
  float asv = as1[c];  // flat [head][c&63] == c
  float adv = ad1[c];
#pragma unroll
  for (int r = 0; r < 16; ++r) {
    h1h[((size_t)head * NN + (base + r)) * 64 + cc] = acc[r];
    float vs = acc[r] * asv, vd = acc[r] * adv;
#pragma unroll
    for (int off = 32; off > 0; off >>= 1) {
      vs += __shfl_xor(vs, off);
      vd += __shfl_xor(vd, off);
    }
    if ((c & 63) == 0) {
      AS1[(base + r) * 4 + head] = vs;
      AD1[(base + r) * 4 + head] = vd;
    }
  }
}

// ---------------- edge weights layer 1: p = exp(lrelu(AS1[s]+AD1[d])), 4 heads ------------
__global__ void k_edgew1(const int* __restrict__ col, const int* __restrict__ dstv,
                         const float* __restrict__ AS1, const float* __restrict__ AD1,
                         float* __restrict__ w1) {
  int i = blockIdx.x * 256 + threadIdx.x;
  if (i >= NEE) return;
  int s = col[i], d = dstv[i];
  float4 as = *(const float4*)(AS1 + s * 4);
  float4 ad = *(const float4*)(AD1 + d * 4);
  float e0 = as.x + ad.x, e1 = as.y + ad.y, e2 = as.z + ad.z, e3 = as.w + ad.w;
  e0 = e0 > 0.f ? e0 : NEG * e0;
  e1 = e1 > 0.f ? e1 : NEG * e1;
  e2 = e2 > 0.f ? e2 : NEG * e2;
  e3 = e3 > 0.f ? e3 : NEG * e3;
  w1[0 * NEE + i] = __expf(e0);
  w1[1 * NEE + i] = __expf(e1);
  w1[2 * NEE + i] = __expf(e2);
  w1[3 * NEE + i] = __expf(e3);
}

// ---------------- GAT layer-1 aggregation: 4 edges x 16 lanes per wave ----------------
__global__ __launch_bounds__(256) void k_agg1(
    const int* __restrict__ rp, const int* __restrict__ col,
    const float* __restrict__ w1, const float* __restrict__ h1h,
    const float* __restrict__ b1, float* __restrict__ out) {
  int wave = threadIdx.x >> 6, lane = threadIdx.x & 63;
  int head = blockIdx.y;
  int n = blockIdx.x * 4 + wave;
  int g = lane >> 4, c4 = (lane & 15) * 4;
  int e0 = rp[n], e1 = rp[n + 1];
  const float* hs = h1h + (size_t)head * NN * 64;
  const float* wp = w1 + (size_t)head * NEE;
  float ax = 0.f, ay = 0.f, az = 0.f, aw = 0.f, den = 0.f;
#pragma unroll 2
  for (int e = e0; e < e1; e += 4) {
    int ee = e + g;
    bool valid = ee < e1;
    int ec = valid ? ee : e1 - 1;
    int s = col[ec];
    float p = valid ? wp[ec] : 0.f;
    float4 hv = *(const float4*)(hs + (size_t)s * 64 + c4);
    ax += p * hv.x; ay += p * hv.y; az += p * hv.z; aw += p * hv.w;
    den += p;
  }
  ax += __shfl_xor(ax, 16); ax += __shfl_xor(ax, 32);
  ay += __shfl_xor(ay, 16); ay += __shfl_xor(ay, 32);
  az += __shfl_xor(az, 16); az += __shfl_xor(az, 32);
  aw += __shfl_xor(aw, 16); aw += __shfl_xor(aw, 32);
  den += __shfl_xor(den, 16); den += __shfl_xor(den, 32);
  if (lane < 16) {
    float inv = 1.f / den;
    int cbase = head * 64 + c4;
    float4 bv = *(const float4*)(b1 + cbase);
    float4 o;
    o.x = ax * inv + bv.x; o.y = ay * inv + bv.y;
    o.z = az * inv + bv.z; o.w = aw * inv + bv.w;
    o.x = o.x > 0.f ? o.x : __expf(o.x) - 1.f;
    o.y = o.y > 0.f ? o.y : __expf(o.y) - 1.f;
    o.z = o.z > 0.f ? o.z : __expf(o.z) - 1.f;
    o.w = o.w > 0.f ? o.w : __expf(o.w) - 1.f;
    *(float4*)(out + (size_t)n * 256 + cbase) = o;
  }
}

// ---------------- GEMM2: h2 = h1act @ W2  [20000,256]x[256,64], + alphas ----------------
__global__ __launch_bounds__(256) void k_gemm2(
    const float* __restrict__ h1a, const float* __restrict__ W2,
    const float* __restrict__ as2, const float* __restrict__ ad2,
    float* __restrict__ h2, float* __restrict__ AS2, float* __restrict__ AD2) {
  __shared__ float xsT[256][20];
  int tid = threadIdx.x;
  int c = tid & 63, w = tid >> 6;  // wave w handles rows 4w..4w+3
  int base = blockIdx.x * 16;
  for (int i = tid; i < 16 * 256; i += 256) {
    int r = i >> 8, k = i & 255;
    xsT[k][r] = h1a[(base + r) * 256 + k];
  }
  __syncthreads();
  float acc[4] = {0.f, 0.f, 0.f, 0.f};
#pragma unroll 2
  for (int k = 0; k < 256; ++k) {
    float wv = W2[k * 64 + c];
    float4 xv = *(const float4*)&xsT[k][w * 4];
    acc[0] += xv.x * wv; acc[1] += xv.y * wv; acc[2] += xv.z * wv; acc[3] += xv.w * wv;
  }
  float asv = as2[c], adv = ad2[c];
#pragma unroll
  for (int rr = 0; rr < 4; ++rr) {
    int row = base + w * 4 + rr;
    h2[row * 64 + c] = acc[rr];
    float vs = acc[rr] * asv, vd = acc[rr] * adv;
#pragma unroll
    for (int off = 32; off > 0; off >>= 1) {
      vs += __shfl_xor(vs, off);
      vd += __shfl_xor(vd, off);
    }
    if (c == 0) { AS2[row] = vs; AD2[row] = vd; }
  }
}

// ---------------- edge weights layer 2 ----------------
__global__ void k_edgew2(const int* __restrict__ col, const int* __restrict__ dstv,
                         const float* __restrict__ AS2, const float* __restrict__ AD2,
                         float* __restrict__ w2) {
  int i = blockIdx.x * 256 + threadIdx.x;
  if (i >= NEE) return;
  int s = col[i], d = dstv[i];
  float ev = AS2[s] + AD2[d];
  ev = ev > 0.f ? ev : NEG * ev;
  w2[i] = __expf(ev);
}

// ---------------- GAT layer-2 aggregation: 4 edges x 16 lanes per wave ----------------
__global__ __launch_bounds__(256) void k_agg2(
    const int* __restrict__ rp, const int* __restrict__ col,
    const float* __restrict__ w2, const float* __restrict__ h2,
    const float* __restrict__ b2, float* __restrict__ out) {
  int wave = threadIdx.x >> 6, lane = threadIdx.x & 63;
  int n = blockIdx.x * 4 + wave;
  int g = lane >> 4, c4 = (lane & 15) * 4;
  int e0 = rp[n], e1 = rp[n + 1];
  float ax = 0.f, ay = 0.f, az = 0.f, aw = 0.f, den = 0.f;
#pragma unroll 2
  for (int e = e0; e < e1; e += 4) {
    int ee = e + g;
    bool valid = ee < e1;
    int ec = valid ? ee : e1 - 1;
    int s = col[ec];
    float p = valid ? w2[ec] : 0.f;
    float4 hv = *(const float4*)(h2 + (size_t)s * 64 + c4);
    ax += p * hv.x; ay += p * hv.y; az += p * hv.z; aw += p * hv.w;
    den += p;
  }
  ax += __shfl_xor(ax, 16); ax += __shfl_xor(ax, 32);
  ay += __shfl_xor(ay, 16); ay += __shfl_xor(ay, 32);
  az += __shfl_xor(az, 16); az += __shfl_xor(az, 32);
  aw += __shfl_xor(aw, 16); aw += __shfl_xor(aw, 32);
  den += __shfl_xor(den, 16); den += __shfl_xor(den, 32);
  if (lane < 16) {
    float inv = 1.f / den;
    float4 bv = *(const float4*)(b2 + c4);
    float4 o;
    o.x = ax * inv + bv.x; o.y = ay * inv + bv.y;
    o.z = az * inv + bv.z; o.w = aw * inv + bv.w;
    o.x = o.x > 0.f ? o.x : __expf(o.x) - 1.f;
    o.y = o.y > 0.f ? o.y : __expf(o.y) - 1.f;
    o.z = o.z > 0.f ? o.z : __expf(o.z) - 1.f;
    o.w = o.w > 0.f ? o.w : __expf(o.w) - 1.f;
    *(float4*)(out + (size_t)n * 64 + c4) = o;
  }
}

// ---------------- pair MLP v9: GEMM-style (k_gemm1 structure) ----------------
// Block = 256 threads, 64 pairs. comb staged ONCE per block into LDS cT[k][pair];
// weights are COALESCED VECTOR loads (per-lane col) hitting L1 (32 KB Wp1 resident);
// comb/z come from LDS broadcast (whole wave reads the same 16B). Scalar pipe idle.
// Live set: acc[16] + 4x float4 staging ~ 40 VGPR -> spill-proof.
// LDS: 32 KB cT + 17 KB zt = 49 KB -> 3 blocks/CU.
__global__ __launch_bounds__(256) void k_pairs(
    const int* __restrict__ pairs, const float* __restrict__ h2a,
    const float* __restrict__ Wp1, const float* __restrict__ bp1,
    const float* __restrict__ Wp2p, const float* __restrict__ bp2p,
    float* __restrict__ out) {
  __shared__ float cT[128][64];   // [k][pair] = comb^T
  __shared__ float zt[64][68];    // [unit][pair], pad 68 keeps float4 alignment
  int tid = threadIdx.x;
  int blk = blockIdx.x;

  // ---- stage comb: thread loads pair p=tid&63, k-chunk q=tid>>6 (32 floats)
  {
    int p = tid & 63, q = tid >> 6;
    int pr = blk * 64 + p;                       // NP = 64*3125 exactly, no guard
    int node = (q < 2) ? pairs[2 * pr] : pairs[2 * pr + 1];
    const float* src = h2a + (size_t)node * 64 + (q & 1) * 32;
    int k0 = q * 32;
#pragma unroll
    for (int m = 0; m < 8; ++m) {
      float4 v = *(const float4*)(src + m * 4);
      cT[k0 + m * 4 + 0][p] = v.x;
      cT[k0 + m * 4 + 1][p] = v.y;
      cT[k0 + m * 4 + 2][p] = v.z;
      cT[k0 + m * 4 + 3][p] = v.w;
    }
  }
  __syncthreads();

  // ---- layer 1: thread (unit c = tid&63, pair-group q = tid>>6) -> acc over 16 pairs
  {
    int c = tid & 63, q = tid >> 6;
    float acc[16];
    float bv = bp1[c];
#pragma unroll
    for (int r = 0; r < 16; ++r) acc[r] = bv;
#pragma unroll 4
    for (int k = 0; k < 128; ++k) {
      float wv = Wp1[k * 64 + c];                // coalesced 256B vector load, L1-hot
      const float4* cr = (const float4*)&cT[k][q * 16];  // wave-broadcast 64B
      float4 c0 = cr[0], c1 = cr[1], c2 = cr[2], c3 = cr[3];
      acc[0] += c0.x * wv; acc[1] += c0.y * wv; acc[2] += c0.z * wv; acc[3] += c0.w * wv;
      acc[4] += c1.x * wv; acc[5] += c1.y * wv; acc[6] += c1.z * wv; acc[7] += c1.w * wv;
      acc[8] += c2.x * wv; acc[9] += c2.y * wv; acc[10] += c2.z * wv; acc[11] += c2.w * wv;
      acc[12] += c3.x * wv; acc[13] += c3.y * wv; acc[14] += c3.z * wv; acc[15] += c3.w * wv;
    }
#pragma unroll
    for (int r = 0; r < 16; ++r) zt[c][q * 16 + r] = fmaxf(acc[r], 0.f);
  }
  __syncthreads();

  // ---- layer 2: 3 passes of 32 cols (Wp2 padded to 96); thread (col c2, pair-group rg)
  {
    int c2 = tid & 31, rg = tid >> 5;            // rg 0..7, 8 pairs each
#pragma unroll 1
    for (int pass = 0; pass < 3; ++pass) {
      int o = pass * 32 + c2;
      float acc2[8];
      float b = bp2p[o];
#pragma unroll
      for (int i = 0; i < 8; ++i) acc2[i] = b;
#pragma unroll 4
      for (int k = 0; k < 64; ++k) {
        float wv = Wp2p[k * 96 + o];             // two 128B segments per wave
        const float4* zr = (const float4*)&zt[k][rg * 8];  // half-wave broadcast 32B
        float4 z0 = zr[0], z1 = zr[1];
        acc2[0] += z0.x * wv; acc2[1] += z0.y * wv; acc2[2] += z0.z * wv; acc2[3] += z0.w * wv;
        acc2[4] += z1.x * wv; acc2[5] += z1.y * wv; acc2[6] += z1.z * wv; acc2[7] += z1.w * wv;
      }
      if (o < 86) {
        int pbase = blk * 64 + rg * 8;
#pragma unroll
        for (int i = 0; i < 8; ++i) out[(size_t)(pbase + i) * 86 + o] = acc2[i];
      }
    }
  }
}

extern "C" void kernel_launch(void* const* d_in, const int* in_sizes, int n_in,
                              void* d_out, int out_size, void* d_ws, size_t ws_size,
                              hipStream_t stream) {
  (void)in_sizes; (void)n_in; (void)out_size; (void)ws_size;
  const float* x      = (const float*)d_in[0];
  const int*   ei     = (const int*)d_in[1];
  const int*   pairs  = (const int*)d_in[2];
  const float* W1     = (const float*)d_in[3];
  const float* a_src1 = (const float*)d_in[4];
  const float* a_dst1 = (const float*)d_in[5];
  const float* b1     = (const float*)d_in[6];
  const float* W2     = (const float*)d_in[7];
  const float* a_src2 = (const float*)d_in[8];
  const float* a_dst2 = (const float*)d_in[9];
  const float* b2     = (const float*)d_in[10];
  const float* Wp1    = (const float*)d_in[11];
  const float* bp1    = (const float*)d_in[12];
  const float* Wp2    = (const float*)d_in[13];
  const float* bp2    = (const float*)d_in[14];
  float* out = (float*)d_out;

  char* w = (char*)d_ws;
  auto alloc = [&](size_t bytes) -> void* {
    void* pp = (void*)w;
    w += (bytes + 255) & ~(size_t)255;
    return pp;
  };
  float* h1    = (float*)alloc((size_t)NN * 256 * 4);  // head-major [4][NN][64]
  float* AS1   = (float*)alloc((size_t)NN * 4 * 4);
  float* AD1   = (float*)alloc((size_t)NN * 4 * 4);
  float* h1agg = (float*)alloc((size_t)NN * 256 * 4);
  float* h2    = (float*)alloc((size_t)NN * 64 * 4);
  float* AS2   = (float*)alloc((size_t)NN * 4);
  float* AD2   = (float*)alloc((size_t)NN * 4);
  float* h2agg = (float*)alloc((size_t)NN * 64 * 4);
  int*   rp    = (int*)alloc((size_t)(NN + 1) * 4);
  int*   cnt   = (int*)alloc((size_t)NN * 4);
  int*   cur   = (int*)alloc((size_t)NN * 4);
  int*   col   = (int*)alloc((size_t)NEE * 4);
  int*   dstv  = (int*)alloc((size_t)NEE * 4);
  float* w1    = (float*)alloc((size_t)4 * NEE * 4);
  float* w2    = (float*)alloc((size_t)NEE * 4);
  float* Wp2p  = (float*)alloc(64 * 96 * 4);
  float* bp2p  = (float*)alloc(96 * 4);

  hipMemsetAsync(cnt, 0, (size_t)NN * 4, stream);
  hipMemsetAsync(cur, 0, (size_t)NN * 4, stream);

  const int EB = (NEE + 255) / 256;  // 2579
  k_hist<<<EB, 256, 0, stream>>>(ei, cnt);
  k_scan<<<1, 1024, 0, stream>>>(cnt, rp);
  k_scatter<<<EB, 256, 0, stream>>>(ei, rp, cur, col, dstv);
  k_prep<<<24, 256, 0, stream>>>(Wp2, bp2, Wp2p, bp2p);

  k_gemm1<<<NN / 16, 256, 0, stream>>>(x, W1, a_src1, a_dst1, h1, AS1, AD1);
  k_edgew1<<<EB, 256, 0, stream>>>(col, dstv, AS1, AD1, w1);
  k_agg1<<<dim3(NN / 4, 4), 256, 0, stream>>>(rp, col, w1, h1, b1, h1agg);

  k_gemm2<<<NN / 16, 256, 0, stream>>>(h1agg, W2, a_src2, a_dst2, h2, AS2, AD2);
  k_edgew2<<<EB, 256, 0, stream>>>(col, dstv, AS2, AD2, w2);
  k_agg2<<<NN / 4, 256, 0, stream>>>(rp, col, w2, h2, b2, h2agg);

  k_pairs<<<NP / 64, 256, 0, stream>>>(pairs, h2agg, Wp1, bp1, Wp2p, bp2p, out);
}